// Round 8
// baseline (176.234 us; speedup 1.0000x reference)
//
#include <hip/hip_runtime.h>
#include <hip/hip_fp16.h>
#include <math.h>

// Problem dims (fixed)
#define B     4096
#define NIN   512
#define L     16
#define N     512
#define K     32
#define NOUT  256
#define TOTAL (NIN + L * N)    // 8704 columns
#define BROWS 8                // batch rows per block (8 int8 bytes = one b64 column)
#define BLOCK 512
#define NROWS (L * N + NOUT)   // 8448 neuron rows
#define XQ    24.0f            // x quant: u = round(x*24)+128, range +-5.33

typedef __attribute__((ext_vector_type(8))) unsigned short u16x8;

__device__ __forceinline__ float sigmoidf_fast(float z) {
    return 1.0f / (1.0f + __expf(-z));
}
__device__ __forceinline__ __half2 bch2(unsigned int u) {
    return __builtin_bit_cast(__half2, u);
}
__device__ __forceinline__ unsigned int h2u(float a, float b) {
    unsigned short lo = __builtin_bit_cast(unsigned short, __float2half(a));
    unsigned short hi = __builtin_bit_cast(unsigned short, __float2half(b));
    return ((unsigned int)hi << 16) | lo;
}

// ---- repack (fully coalesced; kernel is branch-free so entry order is free):
//   w_eff = w * (c<NIN ? 1/XQ : 1/256), duplicated into half2
//   bias fold: b' = b + 0.5 * sum_{act-cols} w   (act stored biased at 128)
__global__ void repack_kernel(const float* __restrict__ W,
                              const int*   __restrict__ idx,
                              const float* __restrict__ b,
                              const float* __restrict__ W_out,
                              const float* __restrict__ b_out,
                              const int*   __restrict__ idx_out,
                              unsigned int*   __restrict__ wh2,
                              unsigned short* __restrict__ i16,
                              float* __restrict__ bq,
                              float* __restrict__ bqo)
{
    const int t = threadIdx.x;
    const int r = blockIdx.x * 8 + (t >> 5);   // neuron row; grid covers 8448 exactly
    const int k = t & 31;

    const bool is_out = (r >= L * N);
    const int  ro     = r - L * N;
    const float w = is_out ? W_out[(size_t)ro * K + k] : W[(size_t)r * K + k];
    const int   c = is_out ? idx_out[(size_t)ro * K + k] : idx[(size_t)r * K + k];

    const float weff = (c < NIN) ? w * (1.0f / XQ) : w * (1.0f / 256.0f);
    wh2[(size_t)r * K + k] = h2u(weff, weff);
    i16[(size_t)r * K + k] = (unsigned short)c;

    float s = (c >= NIN) ? 0.5f * w : 0.0f;
    #pragma unroll
    for (int off = 1; off < 32; off <<= 1) s += __shfl_xor(s, off, 32);
    if (k == 0) {
        if (is_out) bqo[ro] = b_out[ro] + s;
        else        bq[r]   = b[r] + s;
    }
}

// buf[c] = 8 batch rows of column c, one biased-int8 byte each:
//   x cols:   u = round(x*XQ) + 128          -> value = (u-128)/XQ
//   act cols: u = round(a*256) clamp [0,255] -> value-0.5 = (u-128)/256
// Decode per uint32 (4 rows): 2x v_perm -> fp16 {1024+u}, 2x hsub 1152
// (0x6480), 2x pk_fma with pre-scaled dup'd weight. Branch-free (R6's
// divergent dual-path was the regression; R7 proved unified decode).
// LDS 8704*8 = 68 KB -> 2 blocks/CU, 16 waves: co-resident blocks fill
// each other's barrier drains (R7 @1 block/CU stalled 40% of cycles).
__global__ __launch_bounds__(BLOCK, 4)
void ffnet_kernel(const float* __restrict__ x,
                  const unsigned int*   __restrict__ wh2,
                  const unsigned short* __restrict__ i16,
                  const float* __restrict__ bq,
                  const float* __restrict__ bqo,
                  float* __restrict__ out)
{
    __shared__ uint2 buf[TOTAL];   // 68 KB

    const int t  = threadIdx.x;
    const int r0 = blockIdx.x * BROWS;

    // ---- stage x (int8, 8 rows per column); thread t owns column t
    {
        unsigned u8v[8];
        #pragma unroll
        for (int rr = 0; rr < 8; ++rr) {
            const float xv = x[(size_t)(r0 + rr) * NIN + t];
            const float q  = rintf(xv * XQ) + 128.0f;
            u8v[rr] = (unsigned)fmaxf(0.0f, fminf(q, 255.0f));
        }
        uint2 v;
        v.x = u8v[0] | (u8v[1] << 8) | (u8v[2] << 16) | (u8v[3] << 24);
        v.y = u8v[4] | (u8v[5] << 8) | (u8v[6] << 16) | (u8v[7] << 24);
        buf[t] = v;
    }

    // ---- prefetch layer-0 indices (latency overlaps the barrier)
    u16x8 ni[4];
    {
        const u16x8* ip = (const u16x8*)(i16 + (size_t)t * K);
        ni[0] = ip[0]; ni[1] = ip[1]; ni[2] = ip[2]; ni[3] = ip[3];
    }
    __syncthreads();

    const __half2 dbias = bch2(0x64806480u);   // {1152,1152} = 1024+128

#define DECFMA(QW, A0, A1)                                                      \
    {                                                                           \
        const unsigned dlo_ = __builtin_amdgcn_perm(0x64646464u, (QW), 0x05010400u); \
        const unsigned dhi_ = __builtin_amdgcn_perm(0x64646464u, (QW), 0x05030402u); \
        (A0) = __hfma2(__hsub2(bch2(dlo_), dbias), w2_, (A0));                  \
        (A1) = __hfma2(__hsub2(bch2(dhi_), dbias), w2_, (A1));                  \
    }
#define GATHER1(C, W2)                                                          \
    {                                                                           \
        const __half2 w2_ = (W2);                                               \
        const uint2 q_ = buf[(C)];                                              \
        DECFMA(q_.x, a0, a1)                                                    \
        DECFMA(q_.y, a2, a3)                                                    \
    }

    // ---- 16 hidden layers; thread t = neuron t; one barrier per layer
    for (int l = 0; l < L; ++l) {
        u16x8 ci[4] = { ni[0], ni[1], ni[2], ni[3] };

        uint4 wq[8];
        {
            const uint4* wp = (const uint4*)(wh2 + ((size_t)l * N + t) * K);
            #pragma unroll
            for (int g = 0; g < 8; ++g) wq[g] = wp[g];
        }
        const float bb = bq[l * N + t];

        if (l + 1 < L) {   // prefetch next layer's indices
            const u16x8* np = (const u16x8*)(i16 + ((size_t)(l + 1) * N + t) * K);
            ni[0] = np[0]; ni[1] = np[1]; ni[2] = np[2]; ni[3] = np[3];
        }

        __half2 a0 = bch2(0u), a1 = bch2(0u), a2 = bch2(0u), a3 = bch2(0u);
        #pragma unroll
        for (int g = 0; g < 4; ++g) {
            const uint4 wa = wq[2 * g], wb = wq[2 * g + 1];
            GATHER1((int)ci[g][0], bch2(wa.x));
            GATHER1((int)ci[g][1], bch2(wa.y));
            GATHER1((int)ci[g][2], bch2(wa.z));
            GATHER1((int)ci[g][3], bch2(wa.w));
            GATHER1((int)ci[g][4], bch2(wb.x));
            GATHER1((int)ci[g][5], bch2(wb.y));
            GATHER1((int)ci[g][6], bch2(wb.z));
            GATHER1((int)ci[g][7], bch2(wb.w));
        }

        // epilogue: sigmoid -> saturating byte insert (v_cvt_pk_u8_f32)
        const __half2 av[4] = {a0, a1, a2, a3};
        unsigned pkx = 0, pky = 0;
        #pragma unroll
        for (int p = 0; p < 2; ++p) {
            const float s0 = sigmoidf_fast(__low2float(av[p])      + bb);
            const float s1 = sigmoidf_fast(__high2float(av[p])     + bb);
            const float s2 = sigmoidf_fast(__low2float(av[p + 2])  + bb);
            const float s3 = sigmoidf_fast(__high2float(av[p + 2]) + bb);
            // NOTE: av[0],av[1] are rows 0-3 (q.x); av[2],av[3] rows 4-7 (q.y)
            pkx = __builtin_amdgcn_cvt_pk_u8_f32(s0 * 256.0f + 0.5f, 2 * p,     pkx);
            pkx = __builtin_amdgcn_cvt_pk_u8_f32(s1 * 256.0f + 0.5f, 2 * p + 1, pkx);
            pky = __builtin_amdgcn_cvt_pk_u8_f32(s2 * 256.0f + 0.5f, 2 * p,     pky);
            pky = __builtin_amdgcn_cvt_pk_u8_f32(s3 * 256.0f + 0.5f, 2 * p + 1, pky);
        }
        uint2 pk; pk.x = pkx; pk.y = pky;
        buf[NIN + l * N + t] = pk;
        __syncthreads();
    }

    // ---- output layer: threads 0..NOUT-1, fp32 sigmoid out
    if (t < NOUT) {
        const u16x8* ip = (const u16x8*)(i16 + ((size_t)(L * N) + t) * K);
        u16x8 oi[4] = { ip[0], ip[1], ip[2], ip[3] };
        uint4 wq[8];
        {
            const uint4* wp = (const uint4*)(wh2 + ((size_t)(L * N) + t) * K);
            #pragma unroll
            for (int g = 0; g < 8; ++g) wq[g] = wp[g];
        }
        __half2 a0 = bch2(0u), a1 = bch2(0u), a2 = bch2(0u), a3 = bch2(0u);
        #pragma unroll
        for (int g = 0; g < 4; ++g) {
            const uint4 wa = wq[2 * g], wb = wq[2 * g + 1];
            GATHER1((int)oi[g][0], bch2(wa.x));
            GATHER1((int)oi[g][1], bch2(wa.y));
            GATHER1((int)oi[g][2], bch2(wa.z));
            GATHER1((int)oi[g][3], bch2(wa.w));
            GATHER1((int)oi[g][4], bch2(wb.x));
            GATHER1((int)oi[g][5], bch2(wb.y));
            GATHER1((int)oi[g][6], bch2(wb.z));
            GATHER1((int)oi[g][7], bch2(wb.w));
        }
        const float bb = bqo[t];
        out[(size_t)(r0 + 0) * NOUT + t] = sigmoidf_fast(__low2float(a0)  + bb);
        out[(size_t)(r0 + 1) * NOUT + t] = sigmoidf_fast(__high2float(a0) + bb);
        out[(size_t)(r0 + 2) * NOUT + t] = sigmoidf_fast(__low2float(a1)  + bb);
        out[(size_t)(r0 + 3) * NOUT + t] = sigmoidf_fast(__high2float(a1) + bb);
        out[(size_t)(r0 + 4) * NOUT + t] = sigmoidf_fast(__low2float(a2)  + bb);
        out[(size_t)(r0 + 5) * NOUT + t] = sigmoidf_fast(__high2float(a2) + bb);
        out[(size_t)(r0 + 6) * NOUT + t] = sigmoidf_fast(__low2float(a3)  + bb);
        out[(size_t)(r0 + 7) * NOUT + t] = sigmoidf_fast(__high2float(a3) + bb);
    }
#undef GATHER1
#undef DECFMA
}

extern "C" void kernel_launch(void* const* d_in, const int* in_sizes, int n_in,
                              void* d_out, int out_size, void* d_ws, size_t ws_size,
                              hipStream_t stream) {
    const float* x     = (const float*)d_in[0];   // (B, NIN)
    const float* W     = (const float*)d_in[1];   // (L, N, K)
    const float* b     = (const float*)d_in[2];   // (L, N)
    const float* W_out = (const float*)d_in[3];   // (NOUT, K)
    const float* b_out = (const float*)d_in[4];   // (NOUT,)
    const int*   idx   = (const int*)d_in[5];     // (L, N, K)
    const int*   idx_o = (const int*)d_in[6];     // (NOUT, K)
    float* out = (float*)d_out;                   // (B, NOUT)

    // workspace layout (~1.58 MB)
    char* ws = (char*)d_ws;
    unsigned int*   wh2 = (unsigned int*)  (ws);                             // 8448*32*4
    unsigned short* i16 = (unsigned short*)(ws + 1081344);                   // 8448*32*2
    float*          bq  = (float*)         (ws + 1081344 + 540672);          // 32 KB
    float*          bqo = (float*)         (ws + 1081344 + 540672 + 32768);  // 1 KB

    repack_kernel<<<dim3(NROWS / 8), dim3(256), 0, stream>>>(
        W, idx, b, W_out, b_out, idx_o, wh2, i16, bq, bqo);

    ffnet_kernel<<<dim3(B / BROWS), dim3(BLOCK), 0, stream>>>(
        x, wh2, i16, bq, bqo, out);
}